// Round 1
// baseline (51.194 us; speedup 1.0000x reference)
//
#include <hip/hip_runtime.h>

// Problem constants (from reference)
#define BATCH        64
#define T_LEN        512
#define I_LEN        256
#define SEQ          (T_LEN + I_LEN + 2)   // 770
#define EMB_D        768
#define D4           (EMB_D / 4)           // 192 float4 per row
#define IMG_START_ID 30522
#define IMG_END_ID   30523

// Embeddings: out[b, pos, :] = table_row + type_emb[type]
// Grid-stride over float4 elements; 192 consecutive lanes share one table row
// -> coalesced 16B/lane reads and writes.
__global__ void mm_embed_kernel(const int*    __restrict__ text_ids,     // [B, T]
                                const int*    __restrict__ image_tokens, // [B, I]
                                const float4* __restrict__ text_emb,     // [30524, 192]
                                const float4* __restrict__ image_emb,    // [8192, 192]
                                const float4* __restrict__ type_emb,     // [2, 192]
                                float4*       __restrict__ out)          // [B*SEQ*192]
{
    const unsigned total = (unsigned)BATCH * SEQ * D4;   // 9,461,760 < 2^31
    for (unsigned g = blockIdx.x * blockDim.x + threadIdx.x;
         g < total;
         g += gridDim.x * blockDim.x) {
        unsigned row = g / D4;            // [0, B*SEQ)
        unsigned c4  = g - row * D4;      // [0, 192)
        unsigned b   = row / SEQ;
        unsigned pos = row - b * SEQ;

        const float4* src;
        int trow;
        if (pos < T_LEN) {
            int tok = text_ids[b * T_LEN + pos];
            src = text_emb + (unsigned)tok * D4;
            trow = 0;
        } else if (pos == T_LEN) {
            src = text_emb + (unsigned)IMG_START_ID * D4;
            trow = 0;
        } else if (pos < T_LEN + 1 + I_LEN) {
            int tok = image_tokens[b * I_LEN + (pos - T_LEN - 1)];
            src = image_emb + (unsigned)tok * D4;
            trow = 1;
        } else {
            src = text_emb + (unsigned)IMG_END_ID * D4;
            trow = 0;
        }

        float4 v = src[c4];
        float4 t = type_emb[trow * D4 + c4];
        v.x += t.x; v.y += t.y; v.z += t.z; v.w += t.w;
        out[g] = v;
    }
}

// token_types (as float 0/1) then attention_mask (all 1.0), both [B, SEQ].
__global__ void mm_extras_kernel(float* __restrict__ out_types,
                                 float* __restrict__ out_mask)
{
    const unsigned n = (unsigned)BATCH * SEQ;  // 49,280
    for (unsigned i = blockIdx.x * blockDim.x + threadIdx.x;
         i < n;
         i += gridDim.x * blockDim.x) {
        unsigned pos = i % SEQ;
        float ty = (pos > T_LEN && pos <= T_LEN + I_LEN) ? 1.0f : 0.0f;
        out_types[i] = ty;
        out_mask[i]  = 1.0f;
    }
}

extern "C" void kernel_launch(void* const* d_in, const int* in_sizes, int n_in,
                              void* d_out, int out_size, void* d_ws, size_t ws_size,
                              hipStream_t stream) {
    const int*    text_ids     = (const int*)d_in[0];
    const int*    image_tokens = (const int*)d_in[1];
    const float4* text_emb     = (const float4*)d_in[2];
    const float4* image_emb    = (const float4*)d_in[3];
    const float4* type_emb     = (const float4*)d_in[4];

    float* out = (float*)d_out;
    const unsigned emb_elems = (unsigned)BATCH * SEQ * EMB_D;   // 37,847,040
    const unsigned row_elems = (unsigned)BATCH * SEQ;           // 49,280
    float* out_types = out + emb_elems;
    float* out_mask  = out_types + row_elems;

    // Embeddings: memory-bound -> ~2048 blocks, grid-stride (Guideline 11).
    const int block = 256;
    const unsigned total4 = (unsigned)BATCH * SEQ * D4;
    unsigned need = (total4 + block - 1) / block;
    unsigned grid = need < 2048u ? need : 2048u;
    mm_embed_kernel<<<dim3(grid), dim3(block), 0, stream>>>(
        text_ids, image_tokens, text_emb, image_emb, type_emb, (float4*)out);

    unsigned grid2 = (row_elems + block - 1) / block;
    mm_extras_kernel<<<dim3(grid2), dim3(block), 0, stream>>>(out_types, out_mask);
}

// Round 2
// 50.826 us; speedup vs baseline: 1.0072x; 1.0072x over previous
//
#include <hip/hip_runtime.h>

// Problem constants (from reference)
#define BATCH        64
#define T_LEN        512
#define I_LEN        256
#define SEQ          (T_LEN + I_LEN + 2)   // 770
#define EMB_D        768
#define D4           (EMB_D / 4)           // 192 float4 per row
#define IMG_START_ID 30522
#define IMG_END_ID   30523

// Raw vector type so __builtin_nontemporal_store works (HIP's float4 is a
// struct wrapper; the builtin needs a real vector/scalar type).
typedef float f32x4 __attribute__((ext_vector_type(4)));

// Fused kernel:
//   out[b, pos, :] = table_row + type_emb[type]          (nontemporal stores)
//   out_types[b, pos], out_mask[b, pos] written by the c4==0 thread of each row
// Stores are nontemporal (write-around) so the 152 MB output stream does not
// evict the 119 MB of embedding tables from L2/L3 — gather reads then hit
// Infinity Cache on timed replays.
__global__ void mm_fused_kernel(const int*   __restrict__ text_ids,     // [B, T]
                                const int*   __restrict__ image_tokens, // [B, I]
                                const f32x4* __restrict__ text_emb,     // [30524, 192]
                                const f32x4* __restrict__ image_emb,    // [8192, 192]
                                const f32x4* __restrict__ type_emb,     // [2, 192]
                                f32x4*       __restrict__ out_emb,      // [B*SEQ*192]
                                float*       __restrict__ out_types,    // [B*SEQ]
                                float*       __restrict__ out_mask)     // [B*SEQ]
{
    const unsigned total = (unsigned)BATCH * SEQ * D4;   // 9,461,760
    for (unsigned g = blockIdx.x * blockDim.x + threadIdx.x;
         g < total;
         g += gridDim.x * blockDim.x) {
        unsigned row = g / D4;            // [0, B*SEQ)
        unsigned c4  = g - row * D4;      // [0, 192)
        unsigned b   = row / SEQ;
        unsigned pos = row - b * SEQ;

        const f32x4* src;
        unsigned trow;
        if (pos < T_LEN) {
            int tok = text_ids[b * T_LEN + pos];
            src = text_emb + (unsigned)tok * D4;
            trow = 0;
        } else if (pos == T_LEN) {
            src = text_emb + (unsigned)IMG_START_ID * D4;
            trow = 0;
        } else if (pos < T_LEN + 1 + I_LEN) {
            int tok = image_tokens[b * I_LEN + (pos - T_LEN - 1)];
            src = image_emb + (unsigned)tok * D4;
            trow = 1;
        } else {
            src = text_emb + (unsigned)IMG_END_ID * D4;
            trow = 0;
        }

        f32x4 v = src[c4] + type_emb[trow * D4 + c4];
        __builtin_nontemporal_store(v, &out_emb[g]);

        if (c4 == 0) {
            __builtin_nontemporal_store(trow ? 1.0f : 0.0f, &out_types[row]);
            __builtin_nontemporal_store(1.0f, &out_mask[row]);
        }
    }
}

extern "C" void kernel_launch(void* const* d_in, const int* in_sizes, int n_in,
                              void* d_out, int out_size, void* d_ws, size_t ws_size,
                              hipStream_t stream) {
    const int*   text_ids     = (const int*)d_in[0];
    const int*   image_tokens = (const int*)d_in[1];
    const f32x4* text_emb     = (const f32x4*)d_in[2];
    const f32x4* image_emb    = (const f32x4*)d_in[3];
    const f32x4* type_emb     = (const f32x4*)d_in[4];

    float* out = (float*)d_out;
    const unsigned emb_elems = (unsigned)BATCH * SEQ * EMB_D;   // 37,847,040
    const unsigned row_elems = (unsigned)BATCH * SEQ;           // 49,280
    float* out_types = out + emb_elems;
    float* out_mask  = out_types + row_elems;

    const int block = 256;
    const unsigned total4 = (unsigned)BATCH * SEQ * D4;
    unsigned need = (total4 + block - 1) / block;
    unsigned grid = need < 2048u ? need : 2048u;
    mm_fused_kernel<<<dim3(grid), dim3(block), 0, stream>>>(
        text_ids, image_tokens, text_emb, image_emb, type_emb,
        (f32x4*)out, out_types, out_mask);
}